// Round 3
// baseline (114.586 us; speedup 1.0000x reference)
//
#include <hip/hip_runtime.h>
#include <hip/hip_bf16.h>

// HypergraphDecoder: B=2, N=1024, E=256, H=64, D=64, Hm=128
// Outputs (concat, f32): samples[2,1024,1024], mask_scores[2,1024,1024],
//                        entropy[2,1024,1024], w[1024]
//   k1: edge MLP -> w  (tiny)
//   k2: dot_l/dot_r projections, stored as Aexp[b][h][n] = exp2(2*log2e*dot)
//   k3 v3: 32i x 64j tile, grid (32,16,2)=1024 blocks -> 4 blocks/CU,
//       16 waves/CU (was 2 blocks/CU / 8 waves in v1+v2 -- grid-limited).
//       tanh(a+b) = 1 - 2*rcp(exp(2a)*exp(2b)+1): fma+rcp+fma per element.
//       u[] read via one b128 per 4 h instead of b32 per h.

#define L2E 1.4426950408889634f
#define C2  2.8853900817779268f   // 2*log2(e)
#define LN2 0.6931471805599453f
#define RCP(x) __builtin_amdgcn_rcpf(x)
#define EXP2(x) __builtin_amdgcn_exp2f(x)
#define LOG2(x) __builtin_amdgcn_logf(x)

// ---------------- threefry2x32, key = (0,1) (jax.random.key(1)) -------------
__device__ __forceinline__ void threefry2x32_01(unsigned x0, unsigned x1,
                                                unsigned& o0, unsigned& o1) {
  const unsigned k0 = 0u, k1 = 1u;
  const unsigned k2 = 0x1BD11BDAu ^ k0 ^ k1;  // 0x1BD11BDB
#define TF_R(r) { x0 += x1; x1 = (x1 << r) | (x1 >> (32 - r)); x1 ^= x0; }
  x0 += k0; x1 += k1;
  TF_R(13) TF_R(15) TF_R(26) TF_R(6)
  x0 += k1; x1 += k2 + 1u;
  TF_R(17) TF_R(29) TF_R(16) TF_R(24)
  x0 += k2; x1 += k0 + 2u;
  TF_R(13) TF_R(15) TF_R(26) TF_R(6)
  x0 += k0; x1 += k1 + 3u;
  TF_R(17) TF_R(29) TF_R(16) TF_R(24)
  x0 += k1; x1 += k2 + 4u;
  TF_R(13) TF_R(15) TF_R(26) TF_R(6)
  x0 += k2; x1 += k0 + 5u;
#undef TF_R
  o0 = x0; o1 = x1;
}

__device__ __forceinline__ float tf_uniform(unsigned y) {
  // jax uniform f32: bitcast((bits>>9)|0x3f800000) - 1.0
  return __uint_as_float((y >> 9) | 0x3f800000u) - 1.0f;
}

// ---------------- k1: edge MLP -> w[1024] -----------------------------------
__global__ __launch_bounds__(128) void edge_mlp_kernel(
    const float* __restrict__ eq, const float* __restrict__ w1,
    const float* __restrict__ b1, const float* __restrict__ w2,
    const float* __restrict__ b2, float* __restrict__ wout) {
  __shared__ float eql[64];
  __shared__ float part[2];
  const int t = threadIdx.x;
  const int e = blockIdx.x;
  if (t < 64) eql[t] = eq[e * 64 + t];
  __syncthreads();
  float acc = b1[t];
#pragma unroll 8
  for (int k = 0; k < 64; ++k) acc = fmaf(eql[k], w1[k * 128 + t], acc);
  float v = fmaxf(acc, 0.0f) * w2[t];
#pragma unroll
  for (int off = 32; off > 0; off >>= 1) v += __shfl_down(v, off);
  if ((t & 63) == 0) part[t >> 6] = v;
  __syncthreads();
  if (t == 0) {
    const float l = part[0] + part[1] + b2[0];
    const float sp = fmaxf(l, 0.0f) + log1pf(expf(-fabsf(l)));
    wout[e] = sp + 1e-8f;
  }
}

// ---------------- k2: projections + exp, pre-transposed ---------------------
// C[r][c] with r = b*1024+n (2048 rows), c in [0,128): c<64 -> wl, else wr.
// Writes ws[mat*131072 + b*65536 + h*1024 + n] = exp2(C2 * dot).
__global__ __launch_bounds__(256) void proj_exp_kernel(
    const float* __restrict__ enc, const float* __restrict__ wl,
    const float* __restrict__ wr, float* __restrict__ ws) {
  __shared__ float As[32][33];   // [row][e] within chunk
  __shared__ float Ws[32][34];   // [e][col], stride 34 keeps float2 8B-aligned
  const int t = threadIdx.x;
  const int r0 = blockIdx.x * 32;
  const int c0 = blockIdx.y * 32;
  const float* __restrict__ wmat = (c0 < 64) ? wl : wr;
  const int cbase = c0 & 63;
  const int ty = t >> 4, tx = t & 15;
  float acc[2][2] = {};
  for (int ec = 0; ec < 8; ++ec) {
    {
      const int rr = t >> 3, e4 = (t & 7) * 4;
      const float4 v = *(const float4*)(enc + (r0 + rr) * 256 + ec * 32 + e4);
      As[rr][e4] = v.x; As[rr][e4 + 1] = v.y; As[rr][e4 + 2] = v.z; As[rr][e4 + 3] = v.w;
      const float4 w = *(const float4*)(wmat + (ec * 32 + rr) * 64 + cbase + e4);
      Ws[rr][e4] = w.x; Ws[rr][e4 + 1] = w.y; Ws[rr][e4 + 2] = w.z; Ws[rr][e4 + 3] = w.w;
    }
    __syncthreads();
#pragma unroll
    for (int e = 0; e < 32; ++e) {
      const float a0 = As[2 * ty][e];
      const float a1 = As[2 * ty + 1][e];
      const float2 wv = *(const float2*)&Ws[e][2 * tx];
      acc[0][0] = fmaf(a0, wv.x, acc[0][0]);
      acc[0][1] = fmaf(a0, wv.y, acc[0][1]);
      acc[1][0] = fmaf(a1, wv.x, acc[1][0]);
      acc[1][1] = fmaf(a1, wv.y, acc[1][1]);
    }
    __syncthreads();
  }
  const int matoff = (c0 < 64) ? 0 : 131072;
#pragma unroll
  for (int i = 0; i < 2; ++i) {
    const int r = r0 + 2 * ty + i;
    const int b = r >> 10, n = r & 1023;
#pragma unroll
    for (int j = 0; j < 2; ++j) {
      const int c = cbase + 2 * tx + j;
      ws[matoff + b * 65536 + c * 1024 + n] = EXP2(C2 * acc[i][j]);
    }
  }
}

// ---------------- k3: pairwise logits + outputs (v3) ------------------------
// Tile: 32i x 64j, one b per block. grid (32,16,2) = 1024 blocks -> 4/CU,
// 16 waves/CU. LDS 24.3KB. Per thread: 2i x 4j accumulators.
__global__ __launch_bounds__(256) void pair_kernel(
    const float* __restrict__ ws, const float* __restrict__ u,
    const float* __restrict__ lb, float* __restrict__ out) {
  __shared__ float sA[64 * 32];  // [h][i_local]
  __shared__ float sB[64 * 64];  // [h][j_local]
  __shared__ float sU[64];
  const int t = threadIdx.x;
  const int b = blockIdx.z;
  const int i0 = blockIdx.x * 32;
  const int j0 = blockIdx.y * 64;
  const float* __restrict__ srcA = ws + b * 65536;
  const float* __restrict__ srcB = ws + 131072 + b * 65536;

  {
    const int h = t >> 3, c = (t & 7) * 4;
    *(float4*)(sA + h * 32 + c) = *(const float4*)(srcA + h * 1024 + i0 + c);
    *(float4*)(sA + (h + 32) * 32 + c) =
        *(const float4*)(srcA + (h + 32) * 1024 + i0 + c);
  }
  {
    const int h = t >> 4, c = (t & 15) * 4;
#pragma unroll
    for (int q = 0; q < 4; ++q)
      *(float4*)(sB + (h + 16 * q) * 64 + c) =
          *(const float4*)(srcB + (h + 16 * q) * 1024 + j0 + c);
  }
  if (t < 64) sU[t] = u[t];
  __syncthreads();

  const int ia = (t >> 4) * 2;   // 2 consecutive i (broadcast b64 read)
  const int ja = (t & 15) * 4;   // 4 consecutive j (2-way-free b128 read)
  float acc[2][4] = {};          // acc = sum_h u_h * rcp(A*B + 1)
#pragma unroll
  for (int h4 = 0; h4 < 16; ++h4) {
    const float4 uc = *(const float4*)(sU + h4 * 4);  // 4 u's per b128
#pragma unroll
    for (int hh = 0; hh < 4; ++hh) {
      const int h = h4 * 4 + hh;
      const float uh = (&uc.x)[hh];
      const float2 av = *(const float2*)(sA + h * 32 + ia);
      const float4 bv = *(const float4*)(sB + h * 64 + ja);
      const float a[2] = {av.x, av.y};
      const float bb[4] = {bv.x, bv.y, bv.z, bv.w};
#pragma unroll
      for (int ii = 0; ii < 2; ++ii)
#pragma unroll
        for (int jj = 0; jj < 4; ++jj)
          acc[ii][jj] = fmaf(uh, RCP(fmaf(a[ii], bb[jj], 1.0f)), acc[ii][jj]);
    }
  }

  // s = sum(u) + l_bias - 2*acc ; butterfly-reduce sum(u)
  float uv = sU[t & 63];
#pragma unroll
  for (int off = 32; off > 0; off >>= 1) uv += __shfl_xor(uv, off);
  const float su = uv + lb[0];

  float* __restrict__ outS = out + b * 1048576;
  float* __restrict__ outM = out + 2097152 + b * 1048576;
  float* __restrict__ outE = out + 4194304 + b * 1048576;
#pragma unroll
  for (int ii = 0; ii < 2; ++ii) {
    const int gi = i0 + ia + ii;
    const unsigned mb = (unsigned)(gi * 1024 + j0 + ja);
    float4 sv, ev, smv;
#pragma unroll
    for (int jj = 0; jj < 4; ++jj) {
      const int gj = j0 + ja + jj;
      // jax counter pair (m, m+2^20): out0 -> b=0 sample, out1 -> b=1 sample
      unsigned y0, y1;
      threefry2x32_01(mb + (unsigned)jj, mb + (unsigned)jj + 1048576u, y0, y1);
      const float uu = tf_uniform(b ? y1 : y0);
      float s = fmaf(-2.0f, acc[ii][jj], su);
      if (gi == gj) s -= 1e8f;               // diagonal mask
      const float ex = EXP2(-s * L2E);
      const float p = RCP(1.0f + ex);        // sigmoid (inf -> 0 on diag)
      const float em = EXP2(-fabsf(s) * L2E);
      const float ent = fmaxf(s, 0.0f) + LOG2(1.0f + em) * LN2 - s * p;
      (&sv.x)[jj] = s;
      (&ev.x)[jj] = ent;
      (&smv.x)[jj] = (uu < p) ? 1.0f : 0.0f;
    }
    const int base = gi * 1024 + j0 + ja;
    *(float4*)(outS + base) = smv;
    *(float4*)(outM + base) = sv;
    *(float4*)(outE + base) = ev;
  }
}

extern "C" void kernel_launch(void* const* d_in, const int* in_sizes, int n_in,
                              void* d_out, int out_size, void* d_ws, size_t ws_size,
                              hipStream_t stream) {
  const float* enc = (const float*)d_in[0];   // [2,1024,256]
  const float* wl  = (const float*)d_in[1];   // [256,64]
  const float* wr  = (const float*)d_in[2];   // [256,64]
  const float* u   = (const float*)d_in[3];   // [64]
  const float* lb  = (const float*)d_in[4];   // [1]
  const float* eq  = (const float*)d_in[5];   // [1024,64]
  const float* w1  = (const float*)d_in[6];   // [64,128]
  const float* b1  = (const float*)d_in[7];   // [128]
  const float* w2  = (const float*)d_in[8];   // [128,1]
  const float* b2  = (const float*)d_in[9];   // [1]
  float* out = (float*)d_out;
  float* wsf = (float*)d_ws;                  // needs 262144 floats = 1MB

  edge_mlp_kernel<<<1024, 128, 0, stream>>>(eq, w1, b1, w2, b2, out + 6291456);
  proj_exp_kernel<<<dim3(64, 4), 256, 0, stream>>>(enc, wl, wr, wsf);
  pair_kernel<<<dim3(32, 16, 2), 256, 0, stream>>>(wsf, u, lb, out);
}

// Round 4
// 108.939 us; speedup vs baseline: 1.0518x; 1.0518x over previous
//
#include <hip/hip_runtime.h>
#include <hip/hip_bf16.h>

// HypergraphDecoder: B=2, N=1024, E=256, H=64, D=64, Hm=128
// Outputs (concat, f32): samples[2,1024,1024], mask_scores[2,1024,1024],
//                        entropy[2,1024,1024], w[1024]
// R4: 2 launches (was 3).
//   k_prep: fused {proj_exp (256 blocks) + edge MLP (512 blocks)} -- independent.
//   k_pair: 32i x 64j tile, grid (32,16,2)=1024 blocks, 16 waves/CU, 24.3KB LDS.
//       tanh(a+b) = 1 - 2*rcp(exp(2a)*exp(2b)+1): fma+rcp+fma per element.
// Round history: R1 112.3, R2 112.6 (64x64 tile), R3 114.6 (32x64, 2x occupancy)
// -> total invariant to kernel structure; ~95us is harness poison/restore
// overhead (268MB ws fill = 42us visible in every profile), kernels ~15-17us.

#define L2E 1.4426950408889634f
#define C2  2.8853900817779268f   // 2*log2(e)
#define LN2 0.6931471805599453f
#define RCP(x) __builtin_amdgcn_rcpf(x)
#define EXP2(x) __builtin_amdgcn_exp2f(x)
#define LOG2(x) __builtin_amdgcn_logf(x)

// ---------------- threefry2x32, key = (0,1) (jax.random.key(1)) -------------
__device__ __forceinline__ void threefry2x32_01(unsigned x0, unsigned x1,
                                                unsigned& o0, unsigned& o1) {
  const unsigned k0 = 0u, k1 = 1u;
  const unsigned k2 = 0x1BD11BDAu ^ k0 ^ k1;  // 0x1BD11BDB
#define TF_R(r) { x0 += x1; x1 = (x1 << r) | (x1 >> (32 - r)); x1 ^= x0; }
  x0 += k0; x1 += k1;
  TF_R(13) TF_R(15) TF_R(26) TF_R(6)
  x0 += k1; x1 += k2 + 1u;
  TF_R(17) TF_R(29) TF_R(16) TF_R(24)
  x0 += k2; x1 += k0 + 2u;
  TF_R(13) TF_R(15) TF_R(26) TF_R(6)
  x0 += k0; x1 += k1 + 3u;
  TF_R(17) TF_R(29) TF_R(16) TF_R(24)
  x0 += k1; x1 += k2 + 4u;
  TF_R(13) TF_R(15) TF_R(26) TF_R(6)
  x0 += k2; x1 += k0 + 5u;
#undef TF_R
  o0 = x0; o1 = x1;
}

__device__ __forceinline__ float tf_uniform(unsigned y) {
  // jax uniform f32: bitcast((bits>>9)|0x3f800000) - 1.0
  return __uint_as_float((y >> 9) | 0x3f800000u) - 1.0f;
}

// ---------------- k_prep: proj_exp (bx<256) + edge MLP (bx>=256) ------------
// proj: C[r][c], r = b*1024+n (2048 rows), c in [0,128): c<64 -> wl else wr.
//       Writes ws[mat*131072 + b*65536 + h*1024 + n] = exp2(C2 * dot).
// mlp:  2 rows of eq per block (128 threads each), w[1024] -> out tail.
__global__ __launch_bounds__(256) void prep_kernel(
    const float* __restrict__ enc, const float* __restrict__ wl,
    const float* __restrict__ wr, float* __restrict__ ws,
    const float* __restrict__ eq, const float* __restrict__ w1,
    const float* __restrict__ b1, const float* __restrict__ w2,
    const float* __restrict__ b2, float* __restrict__ wout) {
  __shared__ float As[32][33];   // [row][e] within chunk (proj)
  __shared__ float Ws[32][34];   // [e][col] (proj)
  __shared__ float eql[2][64];   // (mlp)
  __shared__ float part[4];      // (mlp)
  const int t = threadIdx.x;
  const int bx = blockIdx.x;

  if (bx < 256) {  // ---------------- projection part ----------------
    const int r0 = (bx & 63) * 32;
    const int c0 = (bx >> 6) * 32;
    const float* __restrict__ wmat = (c0 < 64) ? wl : wr;
    const int cbase = c0 & 63;
    const int ty = t >> 4, tx = t & 15;
    float acc[2][2] = {};
    for (int ec = 0; ec < 8; ++ec) {
      {
        const int rr = t >> 3, e4 = (t & 7) * 4;
        const float4 v = *(const float4*)(enc + (r0 + rr) * 256 + ec * 32 + e4);
        As[rr][e4] = v.x; As[rr][e4 + 1] = v.y; As[rr][e4 + 2] = v.z; As[rr][e4 + 3] = v.w;
        const float4 w = *(const float4*)(wmat + (ec * 32 + rr) * 64 + cbase + e4);
        Ws[rr][e4] = w.x; Ws[rr][e4 + 1] = w.y; Ws[rr][e4 + 2] = w.z; Ws[rr][e4 + 3] = w.w;
      }
      __syncthreads();
#pragma unroll
      for (int e = 0; e < 32; ++e) {
        const float a0 = As[2 * ty][e];
        const float a1 = As[2 * ty + 1][e];
        const float2 wv = *(const float2*)&Ws[e][2 * tx];
        acc[0][0] = fmaf(a0, wv.x, acc[0][0]);
        acc[0][1] = fmaf(a0, wv.y, acc[0][1]);
        acc[1][0] = fmaf(a1, wv.x, acc[1][0]);
        acc[1][1] = fmaf(a1, wv.y, acc[1][1]);
      }
      __syncthreads();
    }
    const int matoff = (c0 < 64) ? 0 : 131072;
#pragma unroll
    for (int i = 0; i < 2; ++i) {
      const int r = r0 + 2 * ty + i;
      const int b = r >> 10, n = r & 1023;
#pragma unroll
      for (int j = 0; j < 2; ++j) {
        const int c = cbase + 2 * tx + j;
        ws[matoff + b * 65536 + c * 1024 + n] = EXP2(C2 * acc[i][j]);
      }
    }
  } else {  // ---------------- edge MLP part ----------------
    const int row = t >> 7;                 // 0..1 within block
    const int e = (bx - 256) * 2 + row;
    const int h = t & 127;
    if (h < 64) eql[row][h] = eq[e * 64 + h];
    __syncthreads();
    float acc = b1[h];
#pragma unroll 8
    for (int k = 0; k < 64; ++k) acc = fmaf(eql[row][k], w1[k * 128 + h], acc);
    float v = fmaxf(acc, 0.0f) * w2[h];
#pragma unroll
    for (int off = 32; off > 0; off >>= 1) v += __shfl_down(v, off);
    if ((t & 63) == 0) part[t >> 6] = v;    // [row0 w0, row0 w1, row1 w0, row1 w1]
    __syncthreads();
    if (h == 0) {
      const float l = part[row * 2] + part[row * 2 + 1] + b2[0];
      const float sp = fmaxf(l, 0.0f) + log1pf(expf(-fabsf(l)));
      wout[e] = sp + 1e-8f;
    }
  }
}

// ---------------- k_pair: pairwise logits + outputs -------------------------
// Tile: 32i x 64j, one b per block. grid (32,16,2) = 1024 blocks -> 4/CU,
// 16 waves/CU. LDS 24.3KB. Per thread: 2i x 4j accumulators.
__global__ __launch_bounds__(256) void pair_kernel(
    const float* __restrict__ ws, const float* __restrict__ u,
    const float* __restrict__ lb, float* __restrict__ out) {
  __shared__ float sA[64 * 32];  // [h][i_local]
  __shared__ float sB[64 * 64];  // [h][j_local]
  __shared__ float sU[64];
  const int t = threadIdx.x;
  const int b = blockIdx.z;
  const int i0 = blockIdx.x * 32;
  const int j0 = blockIdx.y * 64;
  const float* __restrict__ srcA = ws + b * 65536;
  const float* __restrict__ srcB = ws + 131072 + b * 65536;

  {
    const int h = t >> 3, c = (t & 7) * 4;
    *(float4*)(sA + h * 32 + c) = *(const float4*)(srcA + h * 1024 + i0 + c);
    *(float4*)(sA + (h + 32) * 32 + c) =
        *(const float4*)(srcA + (h + 32) * 1024 + i0 + c);
  }
  {
    const int h = t >> 4, c = (t & 15) * 4;
#pragma unroll
    for (int q = 0; q < 4; ++q)
      *(float4*)(sB + (h + 16 * q) * 64 + c) =
          *(const float4*)(srcB + (h + 16 * q) * 1024 + j0 + c);
  }
  if (t < 64) sU[t] = u[t];
  __syncthreads();

  const int ia = (t >> 4) * 2;   // 2 consecutive i (broadcast b64 read)
  const int ja = (t & 15) * 4;   // 4 consecutive j (2-way-free b128 read)
  float acc[2][4] = {};          // acc = sum_h u_h * rcp(A*B + 1)
#pragma unroll
  for (int h4 = 0; h4 < 16; ++h4) {
    const float4 uc = *(const float4*)(sU + h4 * 4);  // 4 u's per b128
#pragma unroll
    for (int hh = 0; hh < 4; ++hh) {
      const int h = h4 * 4 + hh;
      const float uh = (&uc.x)[hh];
      const float2 av = *(const float2*)(sA + h * 32 + ia);
      const float4 bv = *(const float4*)(sB + h * 64 + ja);
      const float a[2] = {av.x, av.y};
      const float bb[4] = {bv.x, bv.y, bv.z, bv.w};
#pragma unroll
      for (int ii = 0; ii < 2; ++ii)
#pragma unroll
        for (int jj = 0; jj < 4; ++jj)
          acc[ii][jj] = fmaf(uh, RCP(fmaf(a[ii], bb[jj], 1.0f)), acc[ii][jj]);
    }
  }

  // s = sum(u) + l_bias - 2*acc ; butterfly-reduce sum(u)
  float uv = sU[t & 63];
#pragma unroll
  for (int off = 32; off > 0; off >>= 1) uv += __shfl_xor(uv, off);
  const float su = uv + lb[0];

  float* __restrict__ outS = out + b * 1048576;
  float* __restrict__ outM = out + 2097152 + b * 1048576;
  float* __restrict__ outE = out + 4194304 + b * 1048576;
#pragma unroll
  for (int ii = 0; ii < 2; ++ii) {
    const int gi = i0 + ia + ii;
    const unsigned mb = (unsigned)(gi * 1024 + j0 + ja);
    float4 sv, ev, smv;
#pragma unroll
    for (int jj = 0; jj < 4; ++jj) {
      const int gj = j0 + ja + jj;
      // jax counter pair (m, m+2^20): out0 -> b=0 sample, out1 -> b=1 sample
      unsigned y0, y1;
      threefry2x32_01(mb + (unsigned)jj, mb + (unsigned)jj + 1048576u, y0, y1);
      const float uu = tf_uniform(b ? y1 : y0);
      float s = fmaf(-2.0f, acc[ii][jj], su);
      if (gi == gj) s -= 1e8f;               // diagonal mask
      const float ex = EXP2(-s * L2E);
      const float p = RCP(1.0f + ex);        // sigmoid (inf -> 0 on diag)
      const float em = EXP2(-fabsf(s) * L2E);
      const float ent = fmaxf(s, 0.0f) + LOG2(1.0f + em) * LN2 - s * p;
      (&sv.x)[jj] = s;
      (&ev.x)[jj] = ent;
      (&smv.x)[jj] = (uu < p) ? 1.0f : 0.0f;
    }
    const int base = gi * 1024 + j0 + ja;
    *(float4*)(outS + base) = smv;
    *(float4*)(outM + base) = sv;
    *(float4*)(outE + base) = ev;
  }
}

extern "C" void kernel_launch(void* const* d_in, const int* in_sizes, int n_in,
                              void* d_out, int out_size, void* d_ws, size_t ws_size,
                              hipStream_t stream) {
  const float* enc = (const float*)d_in[0];   // [2,1024,256]
  const float* wl  = (const float*)d_in[1];   // [256,64]
  const float* wr  = (const float*)d_in[2];   // [256,64]
  const float* u   = (const float*)d_in[3];   // [64]
  const float* lb  = (const float*)d_in[4];   // [1]
  const float* eq  = (const float*)d_in[5];   // [1024,64]
  const float* w1  = (const float*)d_in[6];   // [64,128]
  const float* b1  = (const float*)d_in[7];   // [128]
  const float* w2  = (const float*)d_in[8];   // [128,1]
  const float* b2  = (const float*)d_in[9];   // [1]
  float* out = (float*)d_out;
  float* wsf = (float*)d_ws;                  // needs 262144 floats = 1MB

  prep_kernel<<<768, 256, 0, stream>>>(enc, wl, wr, wsf, eq, w1, b1, w2, b2,
                                       out + 6291456);
  pair_kernel<<<dim3(32, 16, 2), 256, 0, stream>>>(wsf, u, lb, out);
}